// Round 8
// baseline (267.381 us; speedup 1.0000x reference)
//
#include <hip/hip_runtime.h>

#define T_STEPS 128
#define CIN     16
#define HH      64
#define WW      64
#define COUT    64
#define HWSZ    (HH * WW)          // 4096
#define CHW     (COUT * HWSZ)      // 262144
#define XCHW    (CIN * HWSZ)       // 65536

// pass-1: block = one t, 32x32 tile, 32-co half; wave-halves own 16 co each.
#define TILE    32
#define HALO    34
#define LSTR    36                  // padded LDS row stride (floats)
#define PLANE   (HALO * LSTR)       // 1224 floats per ci
#define NST     (CIN * HALO * HALO) // 18496 staged elements
#define WBLK    40                  // padded weight block per (co-group-of-4, ci)

// ---- setup: W[64][16][3][3] -> Wtr[(co>>2)*16+ci][40], inner (co&3)*9+k ----
__global__ void transpose_w(const float* __restrict__ W, float* __restrict__ Wtr) {
    int e = blockIdx.x * 256 + threadIdx.x;     // 0..9215
    if (e >= COUT * CIN * 9) return;
    int co = e / (CIN * 9);
    int r  = e - co * (CIN * 9);
    int ci = r / 9;
    int k  = r - ci * 9;
    Wtr[((co >> 2) * CIN + ci) * WBLK + (co & 3) * 9 + k] = W[e];
}

__global__ __launch_bounds__(512, 4)
void spiking_conv_pass1(const float* __restrict__ x, const float* __restrict__ Wtr,
                        const float* __restrict__ b, float* __restrict__ out) {
    __shared__ float xs[CIN * PLANE];   // 78336 B -> 2 blocks/CU, 16 waves/CU

    const int tid  = threadIdx.x;       // 0..511
    const int t    = blockIdx.y;
    const int coh  = blockIdx.x & 1;    // co-half in FASTEST dim: pair shares x via L3
    const int tile = blockIdx.x >> 1;   // 0..3
    const int h0   = (tile >> 1) * TILE;
    const int w0   = (tile & 1) * TILE;

    // ---- stage all 16 ci (+halo); two unrolled load-batches, loads in flight ----
    const float* xt = x + t * XCHW;
    {
        float vbuf[19]; int ibuf[19];
#pragma unroll
        for (int k = 0; k < 18; ++k) {
            unsigned e = tid + k * 512;
            unsigned ci = e / (HALO * HALO);
            unsigned rem = e - ci * (HALO * HALO);
            unsigned r  = rem / HALO;
            unsigned c  = rem - r * HALO;
            int gh = h0 - 1 + (int)r;
            int gw = w0 - 1 + (int)c;
            bool inb = (unsigned)gh < HH && (unsigned)gw < WW;
            vbuf[k] = inb ? xt[ci * HWSZ + gh * WW + gw] : 0.f;
            ibuf[k] = ci * PLANE + r * LSTR + c;
        }
#pragma unroll
        for (int k = 0; k < 18; ++k) xs[ibuf[k]] = vbuf[k];
#pragma unroll
        for (int k = 0; k < 19; ++k) {
            unsigned e = tid + (18 + k) * 512;
            unsigned ci = e / (HALO * HALO);
            unsigned rem = e - ci * (HALO * HALO);
            unsigned r  = rem / HALO;
            unsigned c  = rem - r * HALO;
            int gh = h0 - 1 + (int)r;
            int gw = w0 - 1 + (int)c;
            bool inb = e < NST && (unsigned)gh < HH && (unsigned)gw < WW;
            vbuf[k] = inb ? xt[ci * HWSZ + gh * WW + gw] : 0.f;
            ibuf[k] = (e < NST) ? (int)(ci * PLANE + r * LSTR + c) : -1;
        }
#pragma unroll
        for (int k = 0; k < 19; ++k)
            if (ibuf[k] >= 0) xs[ibuf[k]] = vbuf[k];
    }
    __syncthreads();

    // ---- compute: wave-half picks 16-co group; thread = 1x4 patch ----
    const int cog = __builtin_amdgcn_readfirstlane(tid >> 8);  // 0/1
    const int sp  = tid & 255;
    const int pr0 = sp >> 3;           // 0..31
    const int pc0 = (sp & 7) * 4;      // 0..28
    float* outt = out + t * CHW;

    float acc[16][4];
#pragma unroll
    for (int j = 0; j < 16; ++j)
#pragma unroll
        for (int p = 0; p < 4; ++p) acc[j][p] = 0.f;

#pragma unroll 1
    for (int ci = 0; ci < CIN; ++ci) {
        // x patch 3x6: ds_read_b128 + ds_read_b64 per row
        float xv[3][6];
#pragma unroll
        for (int dr = 0; dr < 3; ++dr) {
            const float* row = &xs[ci * PLANE + (pr0 + dr) * LSTR + pc0];
            float4 a  = *(const float4*)row;
            float2 c2 = *(const float2*)(row + 4);
            xv[dr][0] = a.x;  xv[dr][1] = a.y;
            xv[dr][2] = a.z;  xv[dr][3] = a.w;
            xv[dr][4] = c2.x; xv[dr][5] = c2.y;
        }
        // 4 co-groups of 4: contiguous 36-float scalar loads (wide s_load)
#pragma unroll
        for (int g = 0; g < 4; ++g) {
            const int g4 = coh * 8 + cog * 4 + g;          // block-uniform
            const float* wb = Wtr + (g4 * CIN + ci) * WBLK;
            float w[36];
#pragma unroll
            for (int i = 0; i < 36; ++i) w[i] = wb[i];
#pragma unroll
            for (int jj = 0; jj < 4; ++jj)
#pragma unroll
                for (int ky = 0; ky < 3; ++ky)
#pragma unroll
                    for (int kx = 0; kx < 3; ++kx) {
                        const float wv = w[jj * 9 + ky * 3 + kx];
#pragma unroll
                        for (int p = 0; p < 4; ++p)
                            acc[g * 4 + jj][p] += wv * xv[ky][kx + p];
                    }
        }
    }

    // ---- epilogue: +bias, float4 stores ----
#pragma unroll
    for (int g = 0; g < 4; ++g)
#pragma unroll
        for (int jj = 0; jj < 4; ++jj) {
            const int co = coh * 32 + cog * 16 + g * 4 + jj;
            const float bias = b[co];
            float4 o;
            o.x = acc[g * 4 + jj][0] + bias;
            o.y = acc[g * 4 + jj][1] + bias;
            o.z = acc[g * 4 + jj][2] + bias;
            o.w = acc[g * 4 + jj][3] + bias;
            *(float4*)&outt[co * HWSZ + (h0 + pr0) * WW + (w0 + pc0)] = o;
        }
}

// ---- pass-2: LDS t-transpose scan ----
// Block owns a 128-float spatial slice x all 128 t (64 KB tile). Global reads
// via async global_load_lds (contiguous 256 B/instr, ~64 in flight per wave);
// scan runs column-wise in LDS (conflict-free); stores 512 B/instr.
#define SCH 128    // spatial slice width (floats)

__device__ __forceinline__ void gl_lds_4(const float* g, float* l) {
    __builtin_amdgcn_global_load_lds(
        (const __attribute__((address_space(1))) void*)g,
        (__attribute__((address_space(3))) void*)l, 4, 0, 0);
}

__global__ __launch_bounds__(256)
void spiking_scan_pass2(float* __restrict__ io) {
    __shared__ float tile[T_STEPS * SCH];   // 65536 B
    const int tid = threadIdx.x;
    const int wv  = tid >> 6;               // wave 0..3
    const int ln  = tid & 63;
    const int s0  = blockIdx.x * SCH;

    // load: wave wv owns t rows [wv*32, wv*32+32); 2 x 256B segments per row
#pragma unroll
    for (int i = 0; i < 32; ++i) {
        const int t = wv * 32 + i;
        const float* g = io + t * CHW + s0;
        float* l = &tile[t * SCH];
        gl_lds_4(g + ln, l);            // lanes cover floats 0..63
        gl_lds_4(g + 64 + ln, l + 64);  // lanes cover floats 64..127
    }
    __syncthreads();   // drains vmcnt (async LDS DMA) + barrier

    // scan: threads 0..127 each own one column
    if (tid < SCH) {
        float s = 0.f;
#pragma unroll 8
        for (int t = 0; t < T_STEPS; ++t) {
            float v = tile[t * SCH + tid];
            s += v;
            const bool sp = (s >= 8.0f);
            tile[t * SCH + tid] = sp ? 1.0f : 0.0f;
            s = sp ? 0.0f : s;              // reset-to-value (0)
            s = fmaxf(s, -1.0f);            // Threshold(-1,-1)
        }
    }
    __syncthreads();

    // store: 512 B per wave-instr (float2 per lane)
#pragma unroll
    for (int i = 0; i < 32; ++i) {
        const int t = wv * 32 + i;
        float2 v = *(const float2*)&tile[t * SCH + ln * 2];
        *(float2*)(io + t * CHW + s0 + ln * 2) = v;
    }
}

extern "C" void kernel_launch(void* const* d_in, const int* in_sizes, int n_in,
                              void* d_out, int out_size, void* d_ws, size_t ws_size,
                              hipStream_t stream) {
    const float* x = (const float*)d_in[0];   // [128,16,64,64]
    const float* W = (const float*)d_in[1];   // [64,16,3,3]
    const float* b = (const float*)d_in[2];   // [64]
    float* out = (float*)d_out;               // [128,64,64,64]
    float* Wtr = (float*)d_ws;                // 16*16*40*4 = 40960 B

    transpose_w<<<36, 256, 0, stream>>>(W, Wtr);

    dim3 g1(8, 128);   // (co-half fastest, 4 tiles) x 128 t = 1024 blocks
    spiking_conv_pass1<<<g1, 512, 0, stream>>>(x, Wtr, b, out);

    spiking_scan_pass2<<<CHW / SCH, 256, 0, stream>>>(out);
}